// Round 10
// baseline (113.352 us; speedup 1.0000x reference)
//
#include <hip/hip_runtime.h>
#include <hip/hip_fp16.h>

// L=8 layers, H=512, K=16 links, N_IN=512, B=8192; out = last 512 cols (fp32).
#define LAYERS 8
#define H      512
#define K      16
#define N_IN   512
#define BATCH  8192
#define R      8      // batch rows per block; 8 x f16 = 16 B -> one ds_read_b128 per gather
#define NT     512    // 8 waves/block; 64 KB LDS -> 2 blocks/CU -> 16 waves/CU
#define LDS_COLS 4096 // layer l gathers from [0, 512+512l) < 4096; layer 7 out -> global

// Ledger:
//   R3/R4 NT=1024: forced 32/36 VGPR + spills. R6/R7/R8 R=4: remat pathology.
//   R9: waves_per_eu(4,4) alone -> VGPR stayed 64 (permission != pressure);
//       scheduler chunks the 16-gather stream into ~4 lgkmcnt-serialized
//       bursts (16 b128 results alone = 64 VGPRs).
//   This round: explicit g[16] + sched_barrier(0) pins issue-all-then-consume;
//   waves_per_eu(4,4) raises the cap to 128 which is free (LDS-bound at
//   2 blocks x 8 waves = 4 waves/EU).

__global__ void __launch_bounds__(NT)
__attribute__((amdgpu_waves_per_eu(4, 4)))
ffn_fused_kernel(const float* __restrict__ x,
                 const int*   __restrict__ link_idx,
                 const float* __restrict__ weights,
                 const float* __restrict__ bias,
                 float*       __restrict__ out)
{
    // vals[c*R + r] = f16 value of column c, block batch-row r.
    __shared__ __align__(16) __half vals[LDS_COLS * R];   // 65536 B

    const int tid  = threadIdx.x;
    const int row0 = blockIdx.x * R;

    // ---- Stage x rows into LDS as f16 (each thread owns one column) ----
    {
        const int c = tid;                     // NT == N_IN == 512
        float v[R];
        #pragma unroll
        for (int r = 0; r < R; ++r)
            v[r] = x[(row0 + r) * N_IN + c];   // coalesced per r
        __half2 p[R / 2];
        #pragma unroll
        for (int r = 0; r < R / 2; ++r)
            p[r] = __floats2half2_rn(v[2 * r], v[2 * r + 1]);
        *(uint4*)&vals[c * R] = *(const uint4*)p;   // one ds_write_b128
    }

    // ---- Preload layer-0 params while LDS staging drains (before barrier) ----
    int   idxA[K]; float wA[K]; float bA;
    {
        const int base = tid * K;              // l=0, h=tid
        #pragma unroll
        for (int q = 0; q < 4; ++q) {
            *(int4*)  &idxA[4 * q] = ((const int4*)  (link_idx + base))[q];
            *(float4*)&wA  [4 * q] = ((const float4*)(weights  + base))[q];
        }
        bA = bias[tid];
    }

    __syncthreads();

    // ---- Layers (each thread owns one h; 8 batch rows in registers) ----
    #pragma unroll
    for (int l = 0; l < LAYERS; ++l) {
        // Prefetch next layer's params; L2 latency hides under this layer's work.
        int idxB[K]; float wB[K]; float bB = 0.0f;
        if (l < LAYERS - 1) {
            const int nb = ((l + 1) * H + tid) * K;
            #pragma unroll
            for (int q = 0; q < 4; ++q) {
                *(int4*)  &idxB[4 * q] = ((const int4*)  (link_idx + nb))[q];
                *(float4*)&wB  [4 * q] = ((const float4*)(weights  + nb))[q];
            }
            bB = bias[(l + 1) * H + tid];
        }

        // ---- Phase 1: issue ALL 16 gathers (64 VGPRs of results in flight) ----
        uint4 g[K];
        #pragma unroll
        for (int k = 0; k < K; ++k)
            g[k] = *(const uint4*)&vals[idxA[k] * R];   // 16x ds_read_b128

        // Forbid the scheduler from sinking consumes into the issue stream
        // (that's the liveness-minimizing move that re-chunks the pipeline).
        __builtin_amdgcn_sched_barrier(0);

        // ---- Phase 2: consume ----
        float acc[R];
        #pragma unroll
        for (int r = 0; r < R; ++r) acc[r] = bA;

        #pragma unroll
        for (int k = 0; k < K; ++k) {
            const __half2* hp = (const __half2*)&g[k];
            const float wk = wA[k];
            #pragma unroll
            for (int r = 0; r < R / 2; ++r) {
                const float2 f = __half22float2(hp[r]);   // folds into v_fma_mix_f32
                acc[2 * r]     = fmaf(f.x, wk, acc[2 * r]);
                acc[2 * r + 1] = fmaf(f.y, wk, acc[2 * r + 1]);
            }
        }

        // sigmoid via v_rcp_f32 (~1 ulp) instead of the exact-divide sequence
        #pragma unroll
        for (int r = 0; r < R; ++r)
            acc[r] = __builtin_amdgcn_rcpf(1.0f + __expf(-acc[r]));

        if (l < LAYERS - 1) {
            __half2 p[R / 2];
            #pragma unroll
            for (int r = 0; r < R / 2; ++r)
                p[r] = __floats2half2_rn(acc[2 * r], acc[2 * r + 1]);
            *(uint4*)&vals[(N_IN + l * H + tid) * R] = *(const uint4*)p;
            __syncthreads();
            // rotate prefetched params in (full unroll -> register renaming)
            #pragma unroll
            for (int k = 0; k < K; ++k) { idxA[k] = idxB[k]; wA[k] = wB[k]; }
            bA = bB;
        } else {
            // final layer: coalesced fp32 stores (lanes -> consecutive h)
            #pragma unroll
            for (int r = 0; r < R; ++r)
                out[(row0 + r) * H + tid] = acc[r];
        }
    }
}

extern "C" void kernel_launch(void* const* d_in, const int* in_sizes, int n_in,
                              void* d_out, int out_size, void* d_ws, size_t ws_size,
                              hipStream_t stream) {
    const float* x        = (const float*)d_in[0];
    const int*   link_idx = (const int*)  d_in[1];
    const float* weights  = (const float*)d_in[2];
    const float* bias     = (const float*)d_in[3];
    float*       out      = (float*)d_out;

    ffn_fused_kernel<<<dim3(BATCH / R), dim3(NT), 0, stream>>>(x, link_idx, weights, bias, out);
}